// Round 3
// baseline (44.584 us; speedup 1.0000x reference)
//
#include <hip/hip_runtime.h>

// Problem dims (fixed by harness setup_inputs)
#define NB 4
#define WR 320
#define NH 240
#define WL 320
#define NLEV 4
#define NK 9
#define TW 64
#define NTILES (WL / TW)        // 5
#define BOXROWS 200             // LDS slots s=0..199 <-> global rows (w0-96)+s
#define NGROUPS (BOXROWS / 4)   // 50 staging groups of 4 rows (1KB each)
#define RSTRIDE ((size_t)NH * WL)  // 76800 floats: corr r-stride == out plane stride

typedef const __attribute__((address_space(1))) void* gas_t;
typedef __attribute__((address_space(3))) void* las_t;

__device__ __forceinline__ void gld_lds16(const float* g, float* l) {
  // async global->LDS, 16B/lane; LDS dest is wave-uniform base + lane*16,
  // global SOURCE address is per-lane (this is what the taper exploits)
  __builtin_amdgcn_global_load_lds((gas_t)g, (las_t)l, 16, 0, 0);
}

template <int L>
__device__ __forceinline__ void sample_level(const float* __restrict__ lds,
                                             int c, int row_lo, float idx_c,
                                             float* __restrict__ outp) {
  const int Wrl = WR >> L;
  const int Wm1 = Wrl - 1;
  const float sc = 1.0f / (float)(1 << L);
  const float fidx = idx_c * sc;

  auto pooled = [&](int j) -> float {
    const int r = (j << L) - row_lo;  // row_lo = w0-96 (may be negative)
    float s = lds[r * TW + c];
#pragma unroll
    for (int t = 1; t < (1 << L); ++t) s += lds[(r + t) * TW + c];
    return s * sc;
  };

  // k=0 index; i0 sequence is non-decreasing with steps in {0,1}
  float idk = fminf(fmaxf(fidx - 4.0f, 0.0f), (float)Wm1);
  int j = (int)idk;
  float vA = pooled(j);
  float vB = pooled(min(j + 1, Wm1));

#pragma unroll
  for (int k = 0; k < NK; ++k) {
    const float idx = fminf(fmaxf(fidx + (float)(k - 4), 0.0f), (float)Wm1);
    const int i0 = (int)idx;
    if (i0 != j) {  // slide the (vA,vB) window
      vA = vB;
      vB = pooled(min(i0 + 1, Wm1));
      j = i0;
    }
    const float w = idx - (float)i0;
    outp[(size_t)k * RSTRIDE] = fmaf(w, vB - vA, vA);
  }
}

extern "C" __global__ __launch_bounds__(256) void corr_sample_kernel(
    const float* __restrict__ corr, const float* __restrict__ disp,
    float* __restrict__ out) {
  __shared__ float lds0[BOXROWS * TW];  // 51.2 KB -> 3 blocks/CU

  const int bid = blockIdx.x;
  const int tile = bid % NTILES;
  const int h = (bid / NTILES) % NH;
  const int b = bid / (NTILES * NH);
  const int w0 = tile * TW;
  const int row_lo = w0 - 96;  // slot s holds global row row_lo + s

  const int tid = (int)threadIdx.x;
  const int lane = tid & 63;
  const int wv = tid >> 6;  // wave id == pyramid level

  // ---- stage tapered band into LDS ----
  // Per-column exact read set: rows [8*floor(c/8)-96, 8*floor(c/8)+47].
  // At 128B-line granularity per 64-col row: cols 0..31 (half0) need only
  // slots s<168; cols 32..63 (half1) need only s>=32. Unneeded half's lanes
  // duplicate the needed half's source (no extra HBM lines).
  {
    const int sub = lane >> 4;       // row within 4-row group
    const int li = lane & 15;        // 16 lanes per 64-col row
    const int c4 = li << 2;          // float col within row
    const bool half1 = (li >= 8);    // cols 32..63
    const size_t bh =
        (size_t)b * WR * RSTRIDE + (size_t)h * WL + w0;  // (b, r=0, h, w0)
    for (int g = wv; g < NGROUPS; g += 4) {
      const int r0 = row_lo + 4 * g;
      if (r0 + 3 < 0 || r0 > WR - 1) continue;  // fully outside image: slots unread
      const int r = r0 + sub;
      const int s = 4 * g + sub;  // slot index
      const bool need = half1 ? (s >= 32) : (s < 168);
      const int cc = need ? c4 : (c4 ^ 32);     // remap to needed half (dup fetch)
      const int rc = min(max(r, 0), WR - 1);    // safety clamp (slots unread)
      const float* src = corr + bh + (size_t)rc * RSTRIDE + cc;
      gld_lds16(src, &lds0[(4 * g) * TW]);
    }
  }
  asm volatile("s_waitcnt vmcnt(0)" ::: "memory");
  __syncthreads();

  // ---- sample: wave wv handles level wv for all 64 columns ----
  const int c = lane;
  const float dsp = disp[((size_t)b * NH + h) * WL + w0 + c];
  const float idx_c = (float)(w0 + c) - dsp;
  float* outp =
      out + ((size_t)(b * (NLEV * NK) + wv * NK) * NH + h) * WL + w0 + c;

  switch (wv) {
    case 0: sample_level<0>(lds0, c, row_lo, idx_c, outp); break;
    case 1: sample_level<1>(lds0, c, row_lo, idx_c, outp); break;
    case 2: sample_level<2>(lds0, c, row_lo, idx_c, outp); break;
    default: sample_level<3>(lds0, c, row_lo, idx_c, outp); break;
  }
}

extern "C" void kernel_launch(void* const* d_in, const int* in_sizes, int n_in,
                              void* d_out, int out_size, void* d_ws,
                              size_t ws_size, hipStream_t stream) {
  const float* corr = (const float*)d_in[0];
  const float* disp = (const float*)d_in[1];
  float* out = (float*)d_out;
  const int grid = NB * NH * NTILES;  // 4800 blocks
  corr_sample_kernel<<<grid, 256, 0, stream>>>(corr, disp, out);
}

// Round 4
// 43.003 us; speedup vs baseline: 1.0368x; 1.0368x over previous
//
#include <hip/hip_runtime.h>

// Problem dims (fixed by harness setup_inputs)
#define NB 4
#define WR 320
#define NH 240
#define WL 320
#define NLEV 4
#define NK 9
#define TW 32
#define NTILES (WL / TW)           // 10
#define HH 2                       // h-rows per block (DRAM page pairing)
#define BAND_LO 96
#define BAND_HI 72
#define ROWS (BAND_LO + BAND_HI)   // 168 band slots (exact at 128B granularity)
#define NGROUPS (ROWS / 4)         // 42 staging groups: 4 slots x 2 h = 1 KB
#define RSTRIDE ((size_t)NH * WL)  // 76800 floats

typedef const __attribute__((address_space(1))) void* gas_t;
typedef __attribute__((address_space(3))) void* las_t;

__device__ __forceinline__ void gld_lds16(const float* g, float* l) {
  // async global->LDS; LDS dest = wave-uniform base + lane*16, source per-lane
  __builtin_amdgcn_global_load_lds((gas_t)g, (las_t)l, 16, 0, 0);
}

// LDS layout: [slot s][hh][c] -> float offset (s<<6) + (hh<<5) + c
// bank = c mod 32 -> conflict-free sampling reads.
template <int L>
__device__ __forceinline__ void sample_level(const float* __restrict__ lds,
                                             int hh, int c, int row_lo,
                                             float idx_c,
                                             float* __restrict__ outp) {
  const int Wrl = WR >> L;
  const int Wm1 = Wrl - 1;
  const float sc = 1.0f / (float)(1 << L);
  const float fidx = idx_c * sc;

  auto pooled = [&](int j) -> float {
    const int s = (j << L) - row_lo;  // slot index, in [0, ROWS) by band algebra
    const int o = (s << 6) + (hh << 5) + c;
    float v = lds[o];
#pragma unroll
    for (int t = 1; t < (1 << L); ++t) v += lds[o + (t << 6)];
    return v * sc;
  };

  // k=0 index; i0 sequence is non-decreasing with steps in {0,1}
  float idk = fminf(fmaxf(fidx - 4.0f, 0.0f), (float)Wm1);
  int j = (int)idk;
  float vA = pooled(j);
  float vB = pooled(min(j + 1, Wm1));

#pragma unroll
  for (int k = 0; k < NK; ++k) {
    const float idx = fminf(fmaxf(fidx + (float)(k - 4), 0.0f), (float)Wm1);
    const int i0 = (int)idx;
    if (i0 != j) {  // slide the (vA,vB) window
      vA = vB;
      vB = pooled(min(i0 + 1, Wm1));
      j = i0;
    }
    const float w = idx - (float)i0;
    outp[(size_t)k * RSTRIDE] = fmaf(w, vB - vA, vA);
  }
}

extern "C" __global__ __launch_bounds__(256) void corr_sample_kernel(
    const float* __restrict__ corr, const float* __restrict__ disp,
    float* __restrict__ out) {
  __shared__ float lds0[ROWS * HH * TW];  // 43 KB -> 3 blocks/CU

  const int bid = blockIdx.x;
  const int tile = bid % NTILES;
  const int hp = (bid / NTILES) % (NH / HH);
  const int b = bid / (NTILES * (NH / HH));
  const int w0 = tile * TW;
  const int h0 = hp * HH;
  const int row_lo = w0 - BAND_LO;  // slot s holds global row row_lo + s

  const int tid = (int)threadIdx.x;
  const int lane = tid & 63;
  const int wv = tid >> 6;  // wave id == pyramid level

  // ---- stage band: one gld_lds = 4 slots x 2 h x 128 B (8 page-paired
  // segments: h-pairs are 1280 B apart -> same DRAM page neighborhood) ----
  {
    const int sub = lane >> 3;   // 0..7 = (ds<<1)|sh
    const int ds = sub >> 1;     // slot within group
    const int sh = sub & 1;      // h within pair
    const int c4 = (lane & 7) << 2;
    for (int g = wv; g < NGROUPS; g += 4) {
      const int r0 = row_lo + 4 * g;
      // group boundaries align with image edges (w0 mult of 32): groups are
      // fully inside or fully outside; outside slots are never sampled
      if (r0 < 0 || r0 > WR - 1) continue;
      const float* src =
          corr + ((size_t)(b * WR + r0 + ds) * NH + (h0 + sh)) * WL + w0 + c4;
      gld_lds16(src, &lds0[g * (4 * HH * TW)]);
    }
  }

  // disp load issues alongside staging loads (drained by the same vmcnt)
  const int hh = lane >> 5;  // half-wave = h within pair
  const int c = lane & 31;   // column within tile
  const float dsp = disp[((size_t)b * NH + (h0 + hh)) * WL + w0 + c];

  asm volatile("s_waitcnt vmcnt(0)" ::: "memory");
  __syncthreads();

  // ---- sample: wave wv = level, half-wave = h; writes are 2x128B
  // page-paired segments per wave instruction ----
  const float idx_c = (float)(w0 + c) - dsp;
  float* outp = out + ((size_t)(b * (NLEV * NK) + wv * NK) * NH + (h0 + hh)) * WL +
                w0 + c;

  switch (wv) {
    case 0: sample_level<0>(lds0, hh, c, row_lo, idx_c, outp); break;
    case 1: sample_level<1>(lds0, hh, c, row_lo, idx_c, outp); break;
    case 2: sample_level<2>(lds0, hh, c, row_lo, idx_c, outp); break;
    default: sample_level<3>(lds0, hh, c, row_lo, idx_c, outp); break;
  }
}

extern "C" void kernel_launch(void* const* d_in, const int* in_sizes, int n_in,
                              void* d_out, int out_size, void* d_ws,
                              size_t ws_size, hipStream_t stream) {
  const float* corr = (const float*)d_in[0];
  const float* disp = (const float*)d_in[1];
  float* out = (float*)d_out;
  const int grid = NB * (NH / HH) * NTILES;  // 4800 blocks
  corr_sample_kernel<<<grid, 256, 0, stream>>>(corr, disp, out);
}

// Round 5
// 42.116 us; speedup vs baseline: 1.0586x; 1.0211x over previous
//
#include <hip/hip_runtime.h>

// Problem dims (fixed by harness setup_inputs)
#define NB 4
#define WR 320
#define NH 240
#define WL 320
#define NLEV 4
#define NK 9
#define TW 16
#define NTILES (WL / TW)           // 20
#define HH 4                       // h-rows per block (DRAM page pairing)
#define BAND_LO 96
#define BAND_HI 56
#define ROWS (BAND_LO + BAND_HI)   // 152 band slots: rows [16t-96, 16t+55], exact
#define NGROUPS (ROWS / 4)         // 38 staging groups: 4 slots x 4 h x 64B = 1 KB
#define RSTRIDE ((size_t)NH * WL)  // 76800 floats
#define NXCD 8

typedef const __attribute__((address_space(1))) void* gas_t;
typedef __attribute__((address_space(3))) void* las_t;

__device__ __forceinline__ void gld_lds16(const float* g, float* l) {
  // async global->LDS; LDS dest = wave-uniform base + lane*16, source per-lane
  __builtin_amdgcn_global_load_lds((gas_t)g, (las_t)l, 16, 0, 0);
}

// LDS layout: [slot s][hh=4][c=16] -> float offset (s<<6) + (hh<<4) + c
// sampling banks: (hh&1)*16 + c -> 2-way alias (hh vs hh+2) = free.
template <int L>
__device__ __forceinline__ void sample_level(const float* __restrict__ lds,
                                             int hh, int c, int row_lo,
                                             float idx_c,
                                             float* __restrict__ outp) {
  const int Wrl = WR >> L;
  const int Wm1 = Wrl - 1;
  const float sc = 1.0f / (float)(1 << L);
  const float fidx = idx_c * sc;

  auto pooled = [&](int j) -> float {
    const int s = (j << L) - row_lo;  // slot index, in [0, ROWS) by band algebra
    const int o = (s << 6) + (hh << 4) + c;
    float v = lds[o];
#pragma unroll
    for (int t = 1; t < (1 << L); ++t) v += lds[o + (t << 6)];
    return v * sc;
  };

  // k=0 index; i0 sequence is non-decreasing with steps in {0,1}
  float idk = fminf(fmaxf(fidx - 4.0f, 0.0f), (float)Wm1);
  int j = (int)idk;
  float vA = pooled(j);
  float vB = pooled(min(j + 1, Wm1));

#pragma unroll
  for (int k = 0; k < NK; ++k) {
    const float idx = fminf(fmaxf(fidx + (float)(k - 4), 0.0f), (float)Wm1);
    const int i0 = (int)idx;
    if (i0 != j) {  // slide the (vA,vB) window
      vA = vB;
      vB = pooled(min(i0 + 1, Wm1));
      j = i0;
    }
    const float w = idx - (float)i0;
    outp[(size_t)k * RSTRIDE] = fmaf(w, vB - vA, vA);
  }
}

extern "C" __global__ __launch_bounds__(256, 4) void corr_sample_kernel(
    const float* __restrict__ corr, const float* __restrict__ disp,
    float* __restrict__ out) {
  __shared__ float lds0[ROWS * HH * TW];  // 38.9 KB -> 4 blocks/CU

  // XCD-aware bijective swizzle: 4800 blocks, 600 per XCD chunk. Adjacent
  // tiles (which share overlapping 128B corr lines) land on the same XCD L2.
  const int bid0 = blockIdx.x;
  const int bid = (bid0 & (NXCD - 1)) * (NB * (NH / HH) * NTILES / NXCD) +
                  (bid0 >> 3);
  const int tile = bid % NTILES;
  const int hp = (bid / NTILES) % (NH / HH);
  const int b = bid / (NTILES * (NH / HH));
  const int w0 = tile * TW;
  const int h0 = hp * HH;
  const int row_lo = w0 - BAND_LO;  // slot s holds global row row_lo + s

  const int tid = (int)threadIdx.x;
  const int lane = tid & 63;
  const int wv = tid >> 6;  // wave id == pyramid level

  // ---- stage band: one gld_lds = 4 slots x 4 h x 64 B. The 4 h-segments
  // per (slot) are 1280 B apart -> 256 B per DRAM page visit. ----
  {
    const int ds = lane >> 4;        // slot within group (0..3)
    const int sh = (lane >> 2) & 3;  // h within quad
    const int c4 = (lane & 3) << 2;  // float col within 16-col row
    for (int g = wv; g < NGROUPS; g += 4) {
      const int r0 = row_lo + 4 * g;
      // row_lo mult of 16 -> groups fully inside or fully outside the image;
      // outside slots are never sampled (clamp algebra)
      if (r0 < 0 || r0 >= WR) continue;
      const float* src =
          corr + ((size_t)(b * WR + r0 + ds) * NH + (h0 + sh)) * WL + w0 + c4;
      gld_lds16(src, &lds0[g * (4 * HH * TW)]);
    }
  }

  // disp load issues alongside staging loads (drained by the same vmcnt)
  const int hh = lane >> 4;  // h within quad (0..3)
  const int c = lane & 15;   // column within tile
  const float dsp = disp[((size_t)b * NH + (h0 + hh)) * WL + w0 + c];

  asm volatile("s_waitcnt vmcnt(0)" ::: "memory");
  __syncthreads();

  // ---- sample: wave wv = level; lane = (hh, c); writes are 4x64B
  // page-paired segments per plane per wave instruction ----
  const float idx_c = (float)(w0 + c) - dsp;
  float* outp = out + ((size_t)(b * (NLEV * NK) + wv * NK) * NH + (h0 + hh)) * WL +
                w0 + c;

  switch (wv) {
    case 0: sample_level<0>(lds0, hh, c, row_lo, idx_c, outp); break;
    case 1: sample_level<1>(lds0, hh, c, row_lo, idx_c, outp); break;
    case 2: sample_level<2>(lds0, hh, c, row_lo, idx_c, outp); break;
    default: sample_level<3>(lds0, hh, c, row_lo, idx_c, outp); break;
  }
}

extern "C" void kernel_launch(void* const* d_in, const int* in_sizes, int n_in,
                              void* d_out, int out_size, void* d_ws,
                              size_t ws_size, hipStream_t stream) {
  const float* corr = (const float*)d_in[0];
  const float* disp = (const float*)d_in[1];
  float* out = (float*)d_out;
  const int grid = NB * (NH / HH) * NTILES;  // 4800 blocks
  corr_sample_kernel<<<grid, 256, 0, stream>>>(corr, disp, out);
}